// Round 6
// baseline (869.968 us; speedup 1.0000x reference)
//
#include <hip/hip_runtime.h>

// Problem constants (match reference setup_inputs)
constexpr int N_NODES = 50000;
constexpr int N_EDGES = 25000;
constexpr int C = 256;   // IN == OUT == 256 channels
constexpr int L = 32;    // incidence list width

// Transposed bf16 weights in device globals.
__device__ ushort W1T_g[C * C];   // [n][k] bf16
__device__ ushort W2T_g[C * C];   // [n][k] bf16

__device__ __forceinline__ ushort f2bf(float f) {
    union { float f; unsigned int u; } c; c.f = f;
    unsigned int r = c.u + 0x7FFFu + ((c.u >> 16) & 1u);   // RNE
    return (ushort)(r >> 16);
}
__device__ __forceinline__ float bflo(unsigned int u) {
    union { unsigned int x; float f; } c; c.x = u << 16; return c.f;
}
__device__ __forceinline__ float bfhi(unsigned int u) {
    union { unsigned int x; float f; } c; c.x = u & 0xFFFF0000u; return c.f;
}
__device__ __forceinline__ void acc_uint4(float* acc, const uint4 v) {
    acc[0] += bflo(v.x); acc[1] += bfhi(v.x);
    acc[2] += bflo(v.y); acc[3] += bfhi(v.y);
    acc[4] += bflo(v.z); acc[5] += bfhi(v.z);
    acc[6] += bflo(v.w); acc[7] += bfhi(v.w);
}

// ---------------------------------------------------------------------------
// x [N,256] fp32 -> xb bf16. 4 elems/thread.
// ---------------------------------------------------------------------------
__global__ __launch_bounds__(256) void convert_x_kernel(
    const float* __restrict__ x, ushort* __restrict__ xb)
{
    const size_t i = ((size_t)blockIdx.x * 256 + threadIdx.x) * 4;
    const float4 v = *reinterpret_cast<const float4*>(x + i);
    ushort4 o;
    o.x = f2bf(v.x); o.y = f2bf(v.y); o.z = f2bf(v.z); o.w = f2bf(v.w);
    *reinterpret_cast<ushort4*>(xb + i) = o;
}

// ---------------------------------------------------------------------------
// Zero the redirect rows: xb[N_NODES,:] and tmp1[N_EDGES,:] (e1 table).
// Must run every launch (ws re-poisoned to 0xAA each timed call).
// ---------------------------------------------------------------------------
__global__ __launch_bounds__(64) void zrow_kernel(
    ushort* __restrict__ z0, ushort* __restrict__ z1)
{
    const int t = threadIdx.x;
    const uint4 z = {0u, 0u, 0u, 0u};
    if (t < 32) reinterpret_cast<uint4*>(z0)[t] = z;
    else        reinterpret_cast<uint4*>(z1)[t - 32] = z;
}

// ---------------------------------------------------------------------------
// W [256k,256n] fp32 row-major -> WT [n][k] bf16 (transposed), via LDS tile.
// ---------------------------------------------------------------------------
__global__ __launch_bounds__(256) void wconv_kernel(
    const float* __restrict__ W1, const float* __restrict__ W2)
{
    const float* W  = blockIdx.z ? W2 : W1;
    ushort* WT      = blockIdx.z ? W2T_g : W1T_g;
    __shared__ float t[64][65];
    const int rr = threadIdx.x >> 6;    // 0..3
    const int cc = threadIdx.x & 63;    // 0..63
    const int br = blockIdx.x * 64;     // k tile
    const int bc = blockIdx.y * 64;     // n tile
#pragma unroll
    for (int i = 0; i < 16; ++i) {
        const int row = i * 4 + rr;
        t[row][cc] = W[(size_t)(br + row) * C + bc + cc];
    }
    __syncthreads();
#pragma unroll
    for (int i = 0; i < 16; ++i) {
        const int n = i * 4 + rr;
        WT[(size_t)(bc + n) * C + br + cc] = f2bf(t[cc][n]);
    }
}

// ---------------------------------------------------------------------------
// gather_edge (gather1): tmp1[row,:] = avg of valid xb[seq[row,:],:]
// UNCHUNKED, half-wave per row, 512B/row granule. (R3/R5 both measured that
// chunking this 25.6MB-table gather regresses: 64B granule at NCHUNK=8, L2
// slice thrash at NCHUNK=4.) Zero-row redirect: invalid ids -> row N (zeroed),
// so the hot loop is pure load+accumulate with no correction registers.
// cnt==0 => reference = row 0 (uniform avg over 32 copies); rare branch.
// ---------------------------------------------------------------------------
__global__ __launch_bounds__(256, 6) void gather_edge_kernel(
    const ushort* __restrict__ src, const int* __restrict__ idx,
    ushort* __restrict__ dst, int nrows, int zrow)
{
    const int row = blockIdx.x * 8 + (threadIdx.x >> 5);
    const int ln  = threadIdx.x & 31;
    if (row >= nrows) return;

    const int myid = idx[(size_t)row * L + ln];
    const unsigned long long b = __ballot(myid > 0);
    const unsigned int halfmask = (unsigned int)(b >> (threadIdx.x & 32));
    const int cnt = __popc(halfmask);
    const int rid = (myid > 0) ? myid : zrow;

    float acc[8] = {0.f, 0.f, 0.f, 0.f, 0.f, 0.f, 0.f, 0.f};
#pragma unroll
    for (int l = 0; l < L; ++l) {
        const int id = __shfl(rid, l, 32);
        const uint4 v = *reinterpret_cast<const uint4*>(
            src + (size_t)id * C + ln * 8);
        acc_uint4(acc, v);
    }

    float inv;
    if (cnt == 0) {            // all-padding: uniform avg == table row 0
        const uint4 v = *reinterpret_cast<const uint4*>(src + ln * 8);
        acc[0] = bflo(v.x); acc[1] = bfhi(v.x); acc[2] = bflo(v.y); acc[3] = bfhi(v.y);
        acc[4] = bflo(v.z); acc[5] = bfhi(v.z); acc[6] = bflo(v.w); acc[7] = bfhi(v.w);
        inv = 1.f;
    } else {
        inv = 1.f / (float)cnt;
    }

    uint4 o;
    o.x = (unsigned)f2bf(acc[0] * inv) | ((unsigned)f2bf(acc[1] * inv) << 16);
    o.y = (unsigned)f2bf(acc[2] * inv) | ((unsigned)f2bf(acc[3] * inv) << 16);
    o.z = (unsigned)f2bf(acc[4] * inv) | ((unsigned)f2bf(acc[5] * inv) << 16);
    o.w = (unsigned)f2bf(acc[6] * inv) | ((unsigned)f2bf(acc[7] * inv) << 16);
    *reinterpret_cast<uint4*>(dst + (size_t)row * C + ln * 8) = o;
}

// ---------------------------------------------------------------------------
// gather_node (gather2): out[row, chunk*64 .. +64] fp32 from e1 table (bf16).
// 4 channel-chunks x 64ch: 3.2MB slice per L2 (R4 measured FETCH==compulsory).
// Zero-row redirect (row E zeroed) + __launch_bounds__ cap fixes R4's
// VGPR=96/20%-occupancy latency stall.
// ---------------------------------------------------------------------------
__global__ __launch_bounds__(256, 6) void gather_node_kernel(
    const ushort* __restrict__ src, const int* __restrict__ idx,
    float* __restrict__ dst, int nrows, int zrow)
{
    constexpr int CH = 64, NCHUNK = 4;
    constexpr int LPR = CH / 8;        // 8 lanes per row
    constexpr int RPB = 256 / LPR;     // 32 rows per block
    const int chunk = blockIdx.x & (NCHUNK - 1);
    const int rb    = (int)(blockIdx.x / NCHUNK) * RPB;
    const int t     = threadIdx.x;

    __shared__ int sidx[RPB][33];
#pragma unroll
    for (int i = 0; i < (RPB * L) / 256; ++i) {
        const int flat = i * 256 + t;
        const int r = flat >> 5, l = flat & 31;
        int raw = (rb + r < nrows) ? idx[(size_t)(rb + r) * L + l] : 0;
        sidx[r][l] = (raw > 0) ? raw : zrow;
    }
    __syncthreads();

    const int r   = t / LPR;
    const int ch  = chunk * CH + (t % LPR) * 8;
    const int row = rb + r;

    float acc[8] = {0.f, 0.f, 0.f, 0.f, 0.f, 0.f, 0.f, 0.f};
    int cnt = 0;
#pragma unroll
    for (int l = 0; l < L; ++l) {
        const int id = sidx[r][l];
        cnt += (id != zrow) ? 1 : 0;
        const uint4 v = *reinterpret_cast<const uint4*>(
            src + (size_t)id * C + ch);
        acc_uint4(acc, v);
    }
    if (row >= nrows) return;

    float inv;
    if (cnt == 0) {            // all-padding: uniform avg == table row 0
        const uint4 v = *reinterpret_cast<const uint4*>(src + ch);
        acc[0] = bflo(v.x); acc[1] = bfhi(v.x); acc[2] = bflo(v.y); acc[3] = bfhi(v.y);
        acc[4] = bflo(v.z); acc[5] = bfhi(v.z); acc[6] = bflo(v.w); acc[7] = bfhi(v.w);
        inv = 1.f;
    } else {
        inv = 1.f / (float)cnt;
    }

    float* d = dst + (size_t)row * C + ch;
    float4 o0 = {acc[0] * inv, acc[1] * inv, acc[2] * inv, acc[3] * inv};
    float4 o1 = {acc[4] * inv, acc[5] * inv, acc[6] * inv, acc[7] * inv};
    *reinterpret_cast<float4*>(d)     = o0;
    *reinterpret_cast<float4*>(d + 4) = o1;
}

// ---------------------------------------------------------------------------
// MFMA bf16 GEMM: C[M,256] = A[M,256] @ W, W transposed bf16 [n][k].
// Wave tile: 32 rows x 128 cols. grid (ceil(M/128), 2).
// C/D: col=lane&15, row=quad*4+reg (m89-verified layout).
// ---------------------------------------------------------------------------
typedef __attribute__((ext_vector_type(8))) short bf16x8;
typedef __attribute__((ext_vector_type(4))) float f32x4;

template <bool RELU>
__global__ __launch_bounds__(256) void gemm_mfma_kernel(
    const ushort* __restrict__ A, int which_w, ushort* __restrict__ Cmat, int M)
{
    const ushort* __restrict__ BT = which_w ? W2T_g : W1T_g;
    const int wave  = threadIdx.x >> 6;
    const int lane  = threadIdx.x & 63;
    const int quad  = lane >> 4;
    const int l16   = lane & 15;
    const int base  = (blockIdx.x * 4 + wave) * 32;
    const int nbase = blockIdx.y * 128;

    int m0 = base + l16;      if (m0 > M - 1) m0 = M - 1;
    int m1 = base + 16 + l16; if (m1 > M - 1) m1 = M - 1;

    f32x4 acc[2][8];
    const f32x4 zero = {0.f, 0.f, 0.f, 0.f};
#pragma unroll
    for (int p = 0; p < 2; ++p)
#pragma unroll
        for (int t = 0; t < 8; ++t) acc[p][t] = zero;

    const ushort* a0 = A + (size_t)m0 * C + quad * 8;
    const ushort* a1 = A + (size_t)m1 * C + quad * 8;
    const ushort* br = BT + (size_t)(nbase + l16) * C + quad * 8;

#pragma unroll
    for (int k0 = 0; k0 < C; k0 += 32) {
        const bf16x8 av0 = *reinterpret_cast<const bf16x8*>(a0 + k0);
        const bf16x8 av1 = *reinterpret_cast<const bf16x8*>(a1 + k0);
#pragma unroll
        for (int t = 0; t < 8; ++t) {
            const bf16x8 b = *reinterpret_cast<const bf16x8*>(
                br + (size_t)t * 16 * C + k0);
            acc[0][t] = __builtin_amdgcn_mfma_f32_16x16x32_bf16(av0, b, acc[0][t], 0, 0, 0);
            acc[1][t] = __builtin_amdgcn_mfma_f32_16x16x32_bf16(av1, b, acc[1][t], 0, 0, 0);
        }
    }

#pragma unroll
    for (int p = 0; p < 2; ++p)
#pragma unroll
    for (int t = 0; t < 8; ++t)
#pragma unroll
    for (int r = 0; r < 4; ++r) {
        const int gm = base + p * 16 + quad * 4 + r;
        if (gm < M) {
            float v = acc[p][t][r];
            if (RELU) v = fmaxf(v, 0.f);
            Cmat[(size_t)gm * C + nbase + t * 16 + l16] = f2bf(v);
        }
    }
}

// ---------------------------------------------------------------------------
// Pipeline (R4 order -- the measured-best structure):
//   xb   = bf16(x)                 [N+1,256] bf16 (row N zeroed: redirect)
//   tmp1 = gather_edge(xb, seq)    [E+1,256] bf16 (row E zeroed: redirect)
//   edge = relu(tmp1 @ W1)         [E,256]   bf16
//   e1   = edge @ W2               -> tmp1 rows 0..E-1 (row E stays zero)
//   out  = gather_node(e1, useq)   [N,256]   fp32 -> d_out
// ws: (N+1 + E+1 + E) * 256 * 2B = 51.2 MB + 1 KB
// ---------------------------------------------------------------------------
extern "C" void kernel_launch(void* const* d_in, const int* in_sizes, int n_in,
                              void* d_out, int out_size, void* d_ws, size_t ws_size,
                              hipStream_t stream) {
    const float* x    = (const float*)d_in[0];
    const int*   seq  = (const int*)d_in[1];
    const int*   useq = (const int*)d_in[2];
    const float* W1   = (const float*)d_in[3];
    const float* W2   = (const float*)d_in[4];
    float* out = (float*)d_out;

    ushort* xb   = (ushort*)d_ws;                        // (N+1) x C
    ushort* tmp1 = xb + (size_t)(N_NODES + 1) * C;       // (E+1) x C
    ushort* edge = tmp1 + (size_t)(N_EDGES + 1) * C;     // E x C

    convert_x_kernel<<<dim3((N_NODES * C) / (256 * 4)), dim3(256), 0, stream>>>(x, xb);
    zrow_kernel<<<dim3(1), dim3(64), 0, stream>>>(
        xb + (size_t)N_NODES * C, tmp1 + (size_t)N_EDGES * C);
    wconv_kernel<<<dim3(4, 4, 2), dim3(256), 0, stream>>>(W1, W2);

    gather_edge_kernel<<<dim3((N_EDGES + 7) / 8), dim3(256), 0, stream>>>(
        xb, seq, tmp1, N_EDGES, N_NODES);

    gemm_mfma_kernel<true><<<dim3((N_EDGES + 127) / 128, 2), dim3(256), 0, stream>>>(
        tmp1, 0, edge, N_EDGES);
    gemm_mfma_kernel<false><<<dim3((N_EDGES + 127) / 128, 2), dim3(256), 0, stream>>>(
        edge, 1, tmp1, N_EDGES);

    gather_node_kernel<<<dim3(4 * ((N_NODES + 31) / 32)), dim3(256), 0, stream>>>(
        tmp1, useq, out, N_NODES, N_EDGES);
}